// Round 6
// baseline (3000.578 us; speedup 1.0000x reference)
//
#include <hip/hip_runtime.h>

// ---------------------------------------------------------------------------
// GNet: RevIN -> 2-layer GRU (B=128, L=512, H=512, I=96) -> proj -> RevIN^-1
// Persistent kernel, 256 blocks x 256 thr, weights in VGPRs as bf16 MFMA
// B-frags, 8 sync groups, one group barrier per timestep.
// Ledger:
// R5 3234us PASS: agent-scope (sc1) exchange; all hops IF/MALL latency.
// R7 WRONG: sc0-flag scope model false (stale L1). R9 4117us: nt = stream-to-
//    HBM (WRITE 135->248MB) but CONFIRMED 32 blocks/XCD placement via roster.
// R10 ~2650us rnn PASS: unique-slot h0 (write-once/read-once addresses) ->
//    plain loads can never hit stale L1 (launch-invalidated, no-write-
//    allocate) -> local-L2 exchange works. Hop saving ~1.1us/phase matched
//    the 4-hop x ~650cy model. Residual ~5us/phase is NOT hop latency.
// R11: the residual theory = barrier ATOMIC CONTENTION: 32 blocks x 8 poll
//    lanes = 256 RMWs/round on 8 lines (32 same-line RMWs serialized at
//    ~30-40cy) -> atomic pipe saturates; arrivals queue behind polls.
//    Fix: contention-free leader/GO barrier:
//      - 32 private arrival lines/group (block j RMWs only line j);
//      - leader (rank 0) polls the 32 lines wave-parallel (lanes 0..31,
//        ballot-reduced), then wave-parallel fetch_add(+1) to 31 private
//        GO lines;
//      - followers poll ONLY their private GO line (1 RMW/round, 2 actors).
//    Data path identical to R10. Fallback identical to R5. Valves on all
//    spins (break -> visible wrong answer, never hang). Guideline 16 holds.
// ---------------------------------------------------------------------------

typedef __attribute__((ext_vector_type(8))) __bf16 bf16x8;
typedef __attribute__((ext_vector_type(4))) float  f32x4;

constexpr int B_  = 128;
constexpr int L_  = 512;
constexpr int H_  = 512;
constexpr int CI_ = 96;    // 16 treat + 16 outcome + 64 covariate
constexpr float EPSR = 1e-5f;
constexpr unsigned GRP_BLKS = 32;   // blocks per sync group

// ---- compact (fallback) ws layout ----
constexpr size_t XN_OFF = 0;                                   // bf16 [L][B][96]
constexpr size_t XN_BYTES = (size_t)L_ * B_ * CI_ * 2;
constexpr size_t YS_OFF = XN_OFF + XN_BYTES;                   // bf16 [L][B][H]
constexpr size_t YS_BYTES = (size_t)L_ * B_ * H_ * 2;
constexpr size_t H0_OFF = YS_OFF + YS_BYTES;                   // bf16 [2][B][H]
constexpr size_t H0_BYTES = (size_t)2 * B_ * H_ * 2;
// barrier: per group 64 lines x 128B (lines 0..31 arrivals, 32..63 GO)
constexpr size_t BAR_BYTES = 8 * 64 * 128;                     // 64 KB
constexpr size_t XCDT_BYTES = 2048;                            // 256 ids + ctr
constexpr size_t STATS_BYTES = 24576 * 4;
// ---- unique-h0 region ----
constexpr size_t H0SLOT_BYTES = (size_t)B_ * H_ * 2;           // 128 KB
constexpr size_t H0U_SLOTS = 513;
constexpr size_t H0U_BYTES = H0U_SLOTS * H0SLOT_BYTES;         // ~67 MB
// stats float offsets
constexpr int ST_TM = 0, ST_TSD = 2048, ST_OM = 4096, ST_OSD = 6144,
              ST_CM = 8192, ST_CSD = 16384;  // total 24576 floats

__device__ inline unsigned short f2bf(float f) {
  unsigned u = __builtin_bit_cast(unsigned, f);
  u += 0x7fffu + ((u >> 16) & 1u);
  return (unsigned short)(u >> 16);
}

union U16x8 { uint4 u4; unsigned long long q[2]; unsigned short s[8]; bf16x8 v; };

__device__ inline bf16x8 load_bf8(const unsigned short* p) {   // plain cached
  U16x8 t; t.u4 = *(const uint4*)p; return t.v;
}
// Agent-coherent (sc1, IF-level) fragment load: 2 x u64 relaxed. (slow path)
__device__ inline bf16x8 load_bf8_coh(const unsigned short* p) {
  U16x8 t;
  const unsigned long long* q = (const unsigned long long*)p;
  t.q[0] = __hip_atomic_load(q + 0, __ATOMIC_RELAXED, __HIP_MEMORY_SCOPE_AGENT);
  t.q[1] = __hip_atomic_load(q + 1, __ATOMIC_RELAXED, __HIP_MEMORY_SCOPE_AGENT);
  return t.v;
}
// Optimizer-opaque zero (SGPR) — keeps poll RMWs as real RMWs.
__device__ __forceinline__ unsigned opaque_zero32() {
  unsigned z;
  asm("s_mov_b32 %0, 0" : "=s"(z));
  return z;
}

__device__ inline bf16x8 cvt_frag(const float* p) {  // 8 consecutive fp32 -> bf16x8
  U16x8 t;
  float4 a = *(const float4*)p;
  float4 b = *(const float4*)(p + 4);
  t.s[0] = f2bf(a.x); t.s[1] = f2bf(a.y); t.s[2] = f2bf(a.z); t.s[3] = f2bf(a.w);
  t.s[4] = f2bf(b.x); t.s[5] = f2bf(b.y); t.s[6] = f2bf(b.z); t.s[7] = f2bf(b.w);
  return t.v;
}
__device__ inline f32x4 mfma16(bf16x8 a, bf16x8 b, f32x4 c) {
  return __builtin_amdgcn_mfma_f32_16x16x32_bf16(a, b, c, 0, 0, 0);
}
__device__ inline float sigm(float x) {
  x = fminf(fmaxf(x, -30.f), 30.f);
  return 1.f / (1.f + __expf(-x));
}
__device__ inline float tanh_(float x) {
  x = fminf(fmaxf(x, -15.f), 15.f);
  float e = __expf(-2.f * x);
  return (1.f - e) / (1.f + e);
}

// Group barrier. vmcnt(0) drains all data stores before arrival (workgroup-
// release). Monotonic counters, no reset.
// FAST (leader/GO, contention-free):
//   - block j: fetch_add(+1) on private arrival line j.
//   - leader (rank 0): lanes 0..31 RMW-poll the 32 arrival lines in parallel,
//     ballot-reduce; when all >= t, lanes 1..31 fetch_add(+1) their GO lines.
//   - follower j: thread 0 RMW-polls private GO line j until >= t.
//   Every line has <= 2 actors -> no same-line RMW storms.
// !FAST: agent scope, exactly R5. Valves: break out, never hang.
template <bool FAST>
__device__ inline void group_bar(unsigned* base, int blkrank, unsigned t) {
  asm volatile("s_waitcnt vmcnt(0)" ::: "memory");
  __syncthreads();
  if (FAST) {
    if (threadIdx.x == 0)
      __hip_atomic_fetch_add(base + blkrank * 32, 1u, __ATOMIC_RELAXED,
                             __HIP_MEMORY_SCOPE_WORKGROUP);
    if (blkrank == 0) {
      if (threadIdx.x < 32) {
        unsigned z = opaque_zero32();
        unsigned spins = 0;
        for (;;) {
          unsigned v = __hip_atomic_fetch_add(base + (int)threadIdx.x * 32, z,
                                              __ATOMIC_RELAXED,
                                              __HIP_MEMORY_SCOPE_WORKGROUP);
          unsigned long long rdy = __ballot((int)(v - t) >= 0);
          if (rdy == 0xFFFFFFFFull) break;
          if (++spins > (1u << 15)) break;   // distress valve
          __builtin_amdgcn_s_sleep(1);
        }
        // release followers: one wave-parallel RMW to 31 private GO lines
        if (threadIdx.x >= 1)
          __hip_atomic_fetch_add(base + (32 + (int)threadIdx.x) * 32, 1u,
                                 __ATOMIC_RELAXED,
                                 __HIP_MEMORY_SCOPE_WORKGROUP);
      }
    } else {
      if (threadIdx.x == 0) {
        unsigned z = opaque_zero32();
        unsigned spins = 0;
        for (;;) {
          unsigned v = __hip_atomic_fetch_add(base + (32 + blkrank) * 32, z,
                                              __ATOMIC_RELAXED,
                                              __HIP_MEMORY_SCOPE_WORKGROUP);
          if ((int)(v - t) >= 0) break;
          if (++spins > (1u << 15)) break;   // distress valve
          __builtin_amdgcn_s_sleep(1);
        }
      }
    }
  } else {
    if (threadIdx.x == 0) {
      const int sub = blkrank & 7;
      const unsigned target = t * GRP_BLKS;
      __hip_atomic_fetch_add(base + sub * 32, 1u, __ATOMIC_RELAXED,
                             __HIP_MEMORY_SCOPE_AGENT);
      unsigned s;
      do {
        __builtin_amdgcn_s_sleep(1);
        s = 0;
#pragma unroll
        for (int i = 0; i < 8; ++i)
          s += __hip_atomic_load(base + i * 32, __ATOMIC_RELAXED,
                                 __HIP_MEMORY_SCOPE_AGENT);
      } while ((int)(s - target) < 0);
    }
  }
  __syncthreads();
  asm volatile("" ::: "memory");   // compiler fence: no load hoisting
}

// ---------------------------------------------------------------------------
// RevIN statistics: mean + std (ddof=1) per (batch, channel), two-pass.
// ---------------------------------------------------------------------------
__global__ void stats_kernel(const float* __restrict__ trt,
                             const float* __restrict__ outh,
                             const float* __restrict__ cov,
                             float* __restrict__ stats) {
  int b = blockIdx.x;
  int ch = threadIdx.x;
  if (ch >= 96) return;
  const float* p; int C; float* mdst; float* sdst; int si;
  if (ch < 16)      { p = trt  + (size_t)b * L_ * 16 + ch;        C = 16; mdst = stats + ST_TM; sdst = stats + ST_TSD; si = b * 16 + ch; }
  else if (ch < 32) { p = outh + (size_t)b * L_ * 16 + (ch - 16); C = 16; mdst = stats + ST_OM; sdst = stats + ST_OSD; si = b * 16 + ch - 16; }
  else              { p = cov  + (size_t)b * L_ * 64 + (ch - 32); C = 64; mdst = stats + ST_CM; sdst = stats + ST_CSD; si = b * 64 + ch - 32; }
  float s = 0.f;
  for (int t = 0; t < L_; ++t) s += p[(size_t)t * C];
  float m = s / (float)L_;
  float q = 0.f;
  for (int t = 0; t < L_; ++t) { float d = p[(size_t)t * C] - m; q += d * d; }
  float sd = sqrtf(q / (float)(L_ - 1));
  mdst[si] = m; sdst[si] = sd;
}

// ---------------------------------------------------------------------------
// Normalize + concat -> xn bf16, layout [t][b][c]
// ---------------------------------------------------------------------------
__global__ void norm_kernel(const float* __restrict__ trt,
                            const float* __restrict__ outh,
                            const float* __restrict__ cov,
                            const float* __restrict__ stats,
                            const float* __restrict__ w_t, const float* __restrict__ b_t,
                            const float* __restrict__ w_o, const float* __restrict__ b_o,
                            const float* __restrict__ w_c, const float* __restrict__ b_c,
                            unsigned short* __restrict__ xn) {
  int idx = blockIdx.x * 256 + threadIdx.x;  // < L*B*96
  int c = idx % CI_;
  int tb = idx / CI_;
  int b = tb % B_;
  int t = tb / B_;
  float v, m, sd, w, bb;
  if (c < 16) {
    v = trt[((size_t)b * L_ + t) * 16 + c];
    m = stats[ST_TM + b * 16 + c]; sd = stats[ST_TSD + b * 16 + c];
    w = w_t[c]; bb = b_t[c];
  } else if (c < 32) {
    int cc = c - 16;
    v = outh[((size_t)b * L_ + t) * 16 + cc];
    m = stats[ST_OM + b * 16 + cc]; sd = stats[ST_OSD + b * 16 + cc];
    w = w_o[cc]; bb = b_o[cc];
  } else {
    int cc = c - 32;
    v = cov[((size_t)b * L_ + t) * 64 + cc];
    m = stats[ST_CM + b * 64 + cc]; sd = stats[ST_CSD + b * 64 + cc];
    w = w_c[cc]; bb = b_c[cc];
  }
  xn[idx] = f2bf((v - m) / (sd + EPSR) * w + bb);
}

// ---------------------------------------------------------------------------
// Persistent GRU kernel. 256 blocks x 256 threads = 4 waves = 2 wave-pairs.
// Group g owns batch tile m0 = g*16; idx (0..31):
//   idx<16  -> cell0, u-tile = idx*2+sub;  idx>=16 -> cell1.
// Phase t=1..513: cell0: h0(t)=cell(x_t, h0(t-1));
//                 cell1: h1(t-1)=cell(h0(t-1), h1(t-2)); one group barrier.
// h0 slot index = t & h0mask (h0mask=1023: unique slot per t; =1: ping-pong).
// ---------------------------------------------------------------------------
template <int ROLE, int NGI, int KI, int NGH, int CH0, bool GATES, bool FAST>
__device__ __forceinline__ void wave_run(
    unsigned* barbase, int blkrank, unsigned h0mask,
    float (*exch)[64][4],
    int lane, int u0, int m0,
    const unsigned short* __restrict__ xn,
    unsigned short* __restrict__ ys,
    unsigned short* __restrict__ h0buf,
    const float* __restrict__ WI, const float* __restrict__ WH,
    const float* __restrict__ bi, const float* __restrict__ bh) {
  const int quad = lane >> 4;
  const int l16 = lane & 15;
  const int b = m0 + l16;      // A-fragment row (batch)
  const int urow = u0 + l16;   // weight row within gate block / output column

  bf16x8 BGI[3][NGI > 0 ? NGI : 1];
  bf16x8 BGH[3][NGH > 0 ? NGH : 1];
  if (NGI > 0) {
#pragma unroll
    for (int g = 0; g < 3; ++g)
#pragma unroll
      for (int c = 0; c < NGI; ++c)
        BGI[g][c] = cvt_frag(WI + (size_t)(g * H_ + urow) * KI + 32 * c + quad * 8);
  }
  if (NGH > 0) {
#pragma unroll
    for (int g = 0; g < 3; ++g)
#pragma unroll
      for (int c = 0; c < NGH; ++c)
        BGH[g][c] = cvt_frag(WH + (size_t)(g * H_ + urow) * H_ + 32 * (CH0 + c) + quad * 8);
  }
  float bi_[3] = {0.f, 0.f, 0.f}, bh_[3] = {0.f, 0.f, 0.f};
  if (GATES) {
#pragma unroll
    for (int g = 0; g < 3; ++g) { bi_[g] = bi[g * H_ + urow]; bh_[g] = bh[g * H_ + urow]; }
  }
  // register-carried previous h at (m0+quad*4+r, urow) — this lane wrote it.
  float hp[4] = {0.f, 0.f, 0.f, 0.f};

  for (int t = 1; t <= 513; ++t) {
    const bool active = (ROLE == 0) ? (t <= 512) : (t >= 2);
    f32x4 agi[3], agh[3];
#pragma unroll
    for (int g = 0; g < 3; ++g) {
      agi[g] = (f32x4){0.f, 0.f, 0.f, 0.f};
      agh[g] = (f32x4){0.f, 0.f, 0.f, 0.f};
    }
    if (active) {
      const bool gh_ok = (NGH > 0) && ((ROLE == 0) || (t >= 3));
      bf16x8 ai[NGI > 0 ? NGI : 1];
      bf16x8 ah[NGH > 0 ? NGH : 1];
      // --- issue all A-fragment loads (batched for issue-parallelism) ---
      if (NGI > 0) {
        const unsigned short* Agi = (ROLE == 0)
            ? xn + ((size_t)(t - 1) * B_ + b) * CI_
            : h0buf + (size_t)((t - 1) & h0mask) * B_ * H_ + (size_t)b * H_;
#pragma unroll
        for (int c = 0; c < NGI; ++c) {
          const unsigned short* p = Agi + 32 * c + quad * 8;
          // FAST: plain load — address unique per t, L1 cannot be stale.
          ai[c] = (ROLE == 0 || FAST) ? load_bf8(p) : load_bf8_coh(p);
        }
      }
      if (gh_ok) {
        const unsigned short* Agh = (ROLE == 0)
            ? h0buf + (size_t)((t - 1) & h0mask) * B_ * H_ + (size_t)b * H_
            : ys + (size_t)(t - 3) * B_ * H_ + (size_t)b * H_;
#pragma unroll
        for (int c = 0; c < NGH; ++c) {
          const unsigned short* p = Agh + 32 * (CH0 + c) + quad * 8;
          ah[c] = FAST ? load_bf8(p) : load_bf8_coh(p);
        }
      }
      // --- MFMAs (compiler inserts the waitcnts) ---
      if (NGI > 0) {
#pragma unroll
        for (int c = 0; c < NGI; ++c) {
          agi[0] = mfma16(ai[c], BGI[0][c], agi[0]);
          agi[1] = mfma16(ai[c], BGI[1][c], agi[1]);
          agi[2] = mfma16(ai[c], BGI[2][c], agi[2]);
        }
      }
      if (gh_ok) {
#pragma unroll
        for (int c = 0; c < NGH; ++c) {
          agh[0] = mfma16(ah[c], BGH[0][c], agh[0]);
          agh[1] = mfma16(ah[c], BGH[1][c], agh[1]);
          agh[2] = mfma16(ah[c], BGH[2][c], agh[2]);
        }
      }
    }
    if (!GATES) {
      // producer wave: publish gh partials to LDS (zeros when inactive)
#pragma unroll
      for (int g = 0; g < 3; ++g)
#pragma unroll
        for (int r = 0; r < 4; ++r) exch[g][lane][r] = agh[g][r];
      __syncthreads();
    } else {
      __syncthreads();
      if (active) {
#pragma unroll
        for (int g = 0; g < 3; ++g)
#pragma unroll
          for (int r = 0; r < 4; ++r) agh[g][r] += exch[g][lane][r];
        unsigned us[4];
#pragma unroll
        for (int r = 0; r < 4; ++r) {
          float rr = sigm(agi[0][r] + bi_[0] + agh[0][r] + bh_[0]);
          float zz = sigm(agi[1][r] + bi_[1] + agh[1][r] + bh_[1]);
          float nn = tanh_(agi[2][r] + bi_[2] + rr * (agh[2][r] + bh_[2]));
          float hv = (1.f - zz) * nn + zz * hp[r];
          hp[r] = hv;
          us[r] = f2bf(hv);
        }
        // pack 2 bf16 along u (adjacent l16 lanes) -> u32 stores.
        unsigned sh0 = (unsigned)__shfl_xor((int)us[0], 1);
        unsigned sh1 = (unsigned)__shfl_xor((int)us[1], 1);
        unsigned sh2 = (unsigned)__shfl_xor((int)us[2], 1);
        unsigned sh3 = (unsigned)__shfl_xor((int)us[3], 1);
        bool odd = (l16 & 1) != 0;
        unsigned ownA = odd ? us[2] : us[0];
        unsigned prtA = odd ? sh2 : sh0;
        unsigned ownB = odd ? us[3] : us[1];
        unsigned prtB = odd ? sh3 : sh1;
        unsigned pkA = odd ? ((prtA & 0xffffu) | (ownA << 16))
                           : ((ownA & 0xffffu) | (prtA << 16));
        unsigned pkB = odd ? ((prtB & 0xffffu) | (ownB << 16))
                           : ((ownB & 0xffffu) | (prtB << 16));
        int rA = odd ? 2 : 0;
        unsigned short* outp = (ROLE == 0)
            ? h0buf + (size_t)(t & h0mask) * B_ * H_
            : ys + (size_t)(t - 2) * B_ * H_;
        unsigned* dst = (unsigned*)outp;
        size_t idxA = (size_t)(m0 + quad * 4 + rA) * (H_ / 2)
                      + ((u0 + (l16 & ~1)) >> 1);
        if (FAST) {
          // plain write-through stores -> local L2; drained by group_bar.
          dst[idxA] = pkA;
          dst[idxA + (H_ / 2)] = pkB;
        } else {
          __hip_atomic_store(dst + idxA, pkA, __ATOMIC_RELAXED,
                             __HIP_MEMORY_SCOPE_AGENT);
          __hip_atomic_store(dst + idxA + (H_ / 2), pkB, __ATOMIC_RELAXED,
                             __HIP_MEMORY_SCOPE_AGENT);
        }
      }
    }
    group_bar<FAST>(barbase, blkrank, (unsigned)t);
  }
}

template <bool FAST>
__device__ __forceinline__ void run_roles(
    int grp, int idx, int wave, int lane, unsigned h0mask,
    float (*exchall)[3][64][4], unsigned* barbase,
    const unsigned short* __restrict__ xn,
    unsigned short* __restrict__ ys,
    unsigned short* __restrict__ h0buf,
    const float* __restrict__ Wih0, const float* __restrict__ Whh0,
    const float* __restrict__ bih0, const float* __restrict__ bhh0,
    const float* __restrict__ Wih1, const float* __restrict__ Whh1,
    const float* __restrict__ bih1, const float* __restrict__ bhh1) {
  const int m0 = grp * 16;
  const int sub = wave >> 1;   // which wave-pair in this block
  const int wr = wave & 1;     // 0 = GATES consumer, 1 = producer
  float (*exch)[64][4] = exchall[sub];

  if (idx < 16) {
    int u0 = (idx * 2 + sub) * 16;
    if (wr == 0)
      wave_run<0, 3, CI_, 8, 0, true, FAST>(barbase, idx, h0mask, exch, lane, u0, m0,
                                            xn, ys, h0buf, Wih0, Whh0, bih0, bhh0);
    else
      wave_run<0, 0, CI_, 8, 8, false, FAST>(barbase, idx, h0mask, exch, lane, u0, m0,
                                             xn, ys, h0buf, Wih0, Whh0, bih0, bhh0);
  } else {
    int u0 = ((idx - 16) * 2 + sub) * 16;
    if (wr == 0)
      wave_run<1, 16, H_, 0, 0, true, FAST>(barbase, idx, h0mask, exch, lane, u0, m0,
                                            xn, ys, h0buf, Wih1, Whh1, bih1, bhh1);
    else
      wave_run<1, 0, H_, 16, 0, false, FAST>(barbase, idx, h0mask, exch, lane, u0, m0,
                                             xn, ys, h0buf, Wih1, Whh1, bih1, bhh1);
  }
}

__launch_bounds__(256, 1)
__global__ void rnn_kernel(const unsigned short* __restrict__ xn,
                           unsigned short* __restrict__ ys,
                           unsigned short* __restrict__ h0buf,
                           unsigned* __restrict__ bar,
                           unsigned* __restrict__ xcdtab,
                           unsigned h0mask, int allowfast,
                           const float* __restrict__ Wih0, const float* __restrict__ Whh0,
                           const float* __restrict__ bih0, const float* __restrict__ bhh0,
                           const float* __restrict__ Wih1, const float* __restrict__ Whh1,
                           const float* __restrict__ bih1, const float* __restrict__ bhh1) {
  __shared__ float exch[2][3][64][4];
  __shared__ unsigned s_x[256];

  // ---- prologue: XCD roster (one-time, agent scope, model-correct fences) ----
  int xcd;
  asm volatile("s_getreg_b32 %0, hwreg(HW_REG_XCC_ID)" : "=s"(xcd));
  xcd &= 7;
  bool sawall = true;
  if (threadIdx.x == 0) {
    __hip_atomic_store(&xcdtab[blockIdx.x], (unsigned)xcd, __ATOMIC_RELAXED,
                       __HIP_MEMORY_SCOPE_AGENT);
    __threadfence();   // release: roster entry at coherence point before arrival
    __hip_atomic_fetch_add(&xcdtab[256], 1u, __ATOMIC_RELAXED,
                           __HIP_MEMORY_SCOPE_AGENT);
    unsigned got, spins = 0;
    do {
      __builtin_amdgcn_s_sleep(8);
      got = __hip_atomic_load(&xcdtab[256], __ATOMIC_RELAXED,
                              __HIP_MEMORY_SCOPE_AGENT);
      if (++spins > (1u << 16)) break;   // distress valve
    } while (got < 256u);
    sawall = (got >= 256u);
    __threadfence();   // acquire: subsequent roster reads see all entries
    s_x[0] = sawall ? 1u : 0u;
  }
  __syncthreads();
  sawall = (s_x[0] != 0u);
  __syncthreads();
  s_x[threadIdx.x] = __hip_atomic_load(&xcdtab[threadIdx.x], __ATOMIC_RELAXED,
                                       __HIP_MEMORY_SCOPE_AGENT);
  __syncthreads();
  if (threadIdx.x == 0) {
    int cnt[8] = {0, 0, 0, 0, 0, 0, 0, 0};
    int rank = 0;
    for (int j = 0; j < 256; ++j) {
      unsigned x = s_x[j] & 7u;
      cnt[x]++;
      if (j < (int)blockIdx.x && x == (unsigned)xcd) rank++;
    }
    bool ok = sawall;
#pragma unroll
    for (int k = 0; k < 8; ++k) ok = ok && (cnt[k] == 32);
    s_x[0] = ok ? 1u : 0u;
    s_x[1] = (unsigned)rank;
  }
  __syncthreads();
  const bool fastp = (s_x[0] != 0u) && (allowfast != 0);
  const int ridx = (int)s_x[1];

  const int wave = threadIdx.x >> 6;
  const int lane = threadIdx.x & 63;

  if (fastp) {
    const int grp = xcd;                 // group = physical XCD -> L2-local
    run_roles<true>(grp, ridx, wave, lane, h0mask, exch, bar + grp * (64 * 32),
                    xn, ys, h0buf, Wih0, Whh0, bih0, bhh0,
                    Wih1, Whh1, bih1, bhh1);
  } else {
    const int grp = (int)(blockIdx.x & 7);
    const int idx = (int)(blockIdx.x >> 3);
    run_roles<false>(grp, idx, wave, lane, h0mask, exch, bar + grp * (64 * 32),
                     xn, ys, h0buf, Wih0, Whh0, bih0, bhh0,
                     Wih1, Whh1, bih1, bhh1);
  }
}

// ---------------------------------------------------------------------------
// Output projection (65536 x 80, K=512) + inverse RevIN, MFMA.
// grid = 512 m-chunks * 5 n-tiles = 2560 blocks x 64 threads (1 wave).
// ---------------------------------------------------------------------------
__global__ void out_kernel(const unsigned short* __restrict__ ys,
                           const float* __restrict__ Wout, const float* __restrict__ bout,
                           const float* __restrict__ w_o, const float* __restrict__ b_o,
                           const float* __restrict__ w_c, const float* __restrict__ b_c,
                           const float* __restrict__ stats,
                           float* __restrict__ dout) {
  int lane = threadIdx.x;
  int quad = lane >> 4, l16 = lane & 15;
  int nb = blockIdx.x % 5, mc = blockIdx.x / 5;
  int ch = nb * 16 + l16;

  bf16x8 BW[16];
#pragma unroll
  for (int c = 0; c < 16; ++c)
    BW[c] = cvt_frag(Wout + (size_t)ch * 512 + 32 * c + quad * 8);
  float bo = bout[ch];
  float rb, rw; const float* mm; const float* ss; int cs, cidx;
  if (ch < 16) { rb = b_o[ch]; rw = w_o[ch]; mm = stats + ST_OM; ss = stats + ST_OSD; cs = 16; cidx = ch; }
  else         { rb = b_c[ch - 16]; rw = w_c[ch - 16]; mm = stats + ST_CM; ss = stats + ST_CSD; cs = 64; cidx = ch - 16; }

  for (int i = 0; i < 8; ++i) {
    int mt = mc * 8 + i;
    const unsigned short* A = ys + (size_t)(mt * 16 + l16) * 512;
    f32x4 acc = {0.f, 0.f, 0.f, 0.f};
#pragma unroll
    for (int c = 0; c < 16; ++c)
      acc = mfma16(load_bf8(A + 32 * c + quad * 8), BW[c], acc);
#pragma unroll
    for (int r = 0; r < 4; ++r) {
      int rr = mt * 16 + quad * 4 + r;
      int t = rr >> 7;
      int b = rr & 127;
      float m = mm[b * cs + cidx], sd = ss[b * cs + cidx];
      float v = (acc[r] + bo - rb) / rw * (sd + EPSR) + m;
      size_t off = (ch < 16)
          ? ((size_t)b * 8192 + (size_t)t * 16 + ch)
          : ((size_t)1048576 + (size_t)b * 32768 + (size_t)t * 64 + (ch - 16));
      dout[off] = v;
    }
  }
}

// ---------------------------------------------------------------------------
extern "C" void kernel_launch(void* const* d_in, const int* in_sizes, int n_in,
                              void* d_out, int out_size, void* d_ws, size_t ws_size,
                              hipStream_t stream) {
  const float* cov  = (const float*)d_in[0];
  const float* trt  = (const float*)d_in[1];
  const float* outh = (const float*)d_in[2];
  const float* Wih0 = (const float*)d_in[3];
  const float* Whh0 = (const float*)d_in[4];
  const float* bih0 = (const float*)d_in[5];
  const float* bhh0 = (const float*)d_in[6];
  const float* Wih1 = (const float*)d_in[7];
  const float* Whh1 = (const float*)d_in[8];
  const float* bih1 = (const float*)d_in[9];
  const float* bhh1 = (const float*)d_in[10];
  const float* Wout = (const float*)d_in[11];
  const float* bout = (const float*)d_in[12];
  const float* w_t  = (const float*)d_in[13];
  const float* b_t  = (const float*)d_in[14];
  const float* w_o  = (const float*)d_in[15];
  const float* b_o  = (const float*)d_in[16];
  const float* w_c  = (const float*)d_in[17];
  const float* b_c  = (const float*)d_in[18];

  char* ws = (char*)d_ws;
  unsigned short* xn = (unsigned short*)(ws + XN_OFF);
  unsigned short* ys = (unsigned short*)(ws + YS_OFF);

  // Unique-h0 layout if workspace allows; else compact (R5) layout.
  const size_t u_h0   = YS_OFF + YS_BYTES;
  const size_t u_bar  = u_h0 + H0U_BYTES;
  const size_t u_xcdt = u_bar + BAR_BYTES;
  const size_t u_st   = u_xcdt + XCDT_BYTES;
  const size_t u_need = u_st + STATS_BYTES;
  const bool uniq = (ws_size >= u_need);

  unsigned short* h0;
  unsigned *bar, *xcdt;
  float* stats;
  unsigned h0mask;
  int allowfast;
  if (uniq) {
    h0    = (unsigned short*)(ws + u_h0);
    bar   = (unsigned*)(ws + u_bar);
    xcdt  = (unsigned*)(ws + u_xcdt);
    stats = (float*)(ws + u_st);
    h0mask = 1023u;        // slot = t (t <= 513)
    allowfast = 1;
    // ws re-poisoned to 0xAA before every launch: zero h0 slot 0 + barriers
    // + roster. (Slots 1..512 are written before read.)
    (void)hipMemsetAsync((void*)(ws + u_h0), 0, H0SLOT_BYTES, stream);
    (void)hipMemsetAsync((void*)(ws + u_bar), 0, BAR_BYTES + XCDT_BYTES, stream);
  } else {
    h0    = (unsigned short*)(ws + H0_OFF);
    bar   = (unsigned*)(ws + H0_OFF + H0_BYTES);
    xcdt  = (unsigned*)(ws + H0_OFF + H0_BYTES + BAR_BYTES);
    stats = (float*)(ws + H0_OFF + H0_BYTES + BAR_BYTES + XCDT_BYTES);
    h0mask = 1u;           // ping-pong (agent-scope fallback only)
    allowfast = 0;
    (void)hipMemsetAsync((void*)(ws + H0_OFF), 0,
                         H0_BYTES + BAR_BYTES + XCDT_BYTES, stream);
  }

  stats_kernel<<<128, 128, 0, stream>>>(trt, outh, cov, stats);
  norm_kernel<<<(L_ * B_ * CI_) / 256, 256, 0, stream>>>(
      trt, outh, cov, stats, w_t, b_t, w_o, b_o, w_c, b_c, xn);

  rnn_kernel<<<256, 256, 0, stream>>>(xn, ys, h0, bar, xcdt, h0mask, allowfast,
                                      Wih0, Whh0, bih0, bhh0,
                                      Wih1, Whh1, bih1, bhh1);

  out_kernel<<<2560, 64, 0, stream>>>(ys, Wout, bout, w_o, b_o, w_c, b_c,
                                      stats, (float*)d_out);
}

// Round 7
// 2635.564 us; speedup vs baseline: 1.1385x; 1.1385x over previous
//
#include <hip/hip_runtime.h>

// ---------------------------------------------------------------------------
// GNet: RevIN -> 2-layer GRU (B=128, L=512, H=512, I=96) -> proj -> RevIN^-1
// Persistent kernel, 256 blocks x 256 thr, weights in VGPRs as bf16 MFMA
// B-frags, 8 sync groups, one group barrier per timestep.
// Ledger:
// R5 3234us PASS: agent-scope (sc1) exchange; all hops IF/MALL latency.
// R7 WRONG: sc0-on-loads = scope not L1-bypass (stale L1). R9 4117us: nt =
//    stream-to-HBM; CONFIRMED 32 blocks/XCD placement via roster.
// R10 ~2650us PASS: unique-slot h0 + plain ops. Only +1.1us/phase.
// R11 ~2910us PASS: leader/GO barrier REGRESSED (+0.4us/phase) -> barrier was
//    never dominant; revert to R10 barrier.
// KEY R10/R11 counter fact: FETCH_SIZE stayed ~111MB = xn + h0 + ys first
//    reads ALL still miss L2. Model correction: plain stores on gfx950 are
//    WRITE-THROUGH NO-ALLOCATE at L2 -> data never lands in local L2; every
//    phase still pays MALL store-drain + MALL first-read. Barrier atomics
//    (L2-executing RMWs) were the only thing that actually moved to L2.
// R12: make DATA stores L2-executing too: non-returning atomicExch
//    (workgroup scope, relaxed) -> global_atomic_swap executes in the XCD's
//    TCC atomic unit and allocates the line DIRTY in local L2. Consumers'
//    plain loads (unique addresses -> no stale L1 possible) then HIT L2.
//    <=8 RMWs per 128B line per wave -> no atomic-unit serialization issue.
//    Cross-dispatch visibility (out_kernel reads ys): CP inter-dispatch L2
//    writeback/invalidate, standard HIP stream semantics.
//    Fallback = exact R5 agent-scope path. Guideline 16 holds.
// ---------------------------------------------------------------------------

typedef __attribute__((ext_vector_type(8))) __bf16 bf16x8;
typedef __attribute__((ext_vector_type(4))) float  f32x4;

constexpr int B_  = 128;
constexpr int L_  = 512;
constexpr int H_  = 512;
constexpr int CI_ = 96;    // 16 treat + 16 outcome + 64 covariate
constexpr float EPSR = 1e-5f;
constexpr unsigned GRP_BLKS = 32;   // blocks per sync group

// ---- compact (fallback) ws layout ----
constexpr size_t XN_OFF = 0;                                   // bf16 [L][B][96]
constexpr size_t XN_BYTES = (size_t)L_ * B_ * CI_ * 2;
constexpr size_t YS_OFF = XN_OFF + XN_BYTES;                   // bf16 [L][B][H]
constexpr size_t YS_BYTES = (size_t)L_ * B_ * H_ * 2;
constexpr size_t H0_OFF = YS_OFF + YS_BYTES;                   // bf16 [2][B][H]
constexpr size_t H0_BYTES = (size_t)2 * B_ * H_ * 2;
// barrier: per group 64 lines x 128B (only lines 0..7 used as sum sub-lines)
constexpr size_t BAR_BYTES = 8 * 64 * 128;                     // 64 KB
constexpr size_t XCDT_BYTES = 2048;                            // 256 ids + ctr
constexpr size_t STATS_BYTES = 24576 * 4;
// ---- unique-h0 region ----
constexpr size_t H0SLOT_BYTES = (size_t)B_ * H_ * 2;           // 128 KB
constexpr size_t H0U_SLOTS = 513;
constexpr size_t H0U_BYTES = H0U_SLOTS * H0SLOT_BYTES;         // ~67 MB
// stats float offsets
constexpr int ST_TM = 0, ST_TSD = 2048, ST_OM = 4096, ST_OSD = 6144,
              ST_CM = 8192, ST_CSD = 16384;  // total 24576 floats

__device__ inline unsigned short f2bf(float f) {
  unsigned u = __builtin_bit_cast(unsigned, f);
  u += 0x7fffu + ((u >> 16) & 1u);
  return (unsigned short)(u >> 16);
}

union U16x8 { uint4 u4; unsigned long long q[2]; unsigned short s[8]; bf16x8 v; };

__device__ inline bf16x8 load_bf8(const unsigned short* p) {   // plain cached
  U16x8 t; t.u4 = *(const uint4*)p; return t.v;
}
// Agent-coherent (sc1, IF-level) fragment load: 2 x u64 relaxed. (slow path)
__device__ inline bf16x8 load_bf8_coh(const unsigned short* p) {
  U16x8 t;
  const unsigned long long* q = (const unsigned long long*)p;
  t.q[0] = __hip_atomic_load(q + 0, __ATOMIC_RELAXED, __HIP_MEMORY_SCOPE_AGENT);
  t.q[1] = __hip_atomic_load(q + 1, __ATOMIC_RELAXED, __HIP_MEMORY_SCOPE_AGENT);
  return t.v;
}
// Optimizer-opaque zero (SGPR) — keeps poll RMWs as real RMWs.
__device__ __forceinline__ unsigned opaque_zero32() {
  unsigned z;
  asm("s_mov_b32 %0, 0" : "=s"(z));
  return z;
}
// L2-allocating data store: non-returning atomic swap executes in the local
// TCC atomic unit and leaves the line dirty in the XCD's L2.
__device__ __forceinline__ void store_u32_l2rmw(unsigned* p, unsigned v) {
  (void)__hip_atomic_exchange(p, v, __ATOMIC_RELAXED,
                              __HIP_MEMORY_SCOPE_WORKGROUP);
}

__device__ inline bf16x8 cvt_frag(const float* p) {  // 8 consecutive fp32 -> bf16x8
  U16x8 t;
  float4 a = *(const float4*)p;
  float4 b = *(const float4*)(p + 4);
  t.s[0] = f2bf(a.x); t.s[1] = f2bf(a.y); t.s[2] = f2bf(a.z); t.s[3] = f2bf(a.w);
  t.s[4] = f2bf(b.x); t.s[5] = f2bf(b.y); t.s[6] = f2bf(b.z); t.s[7] = f2bf(b.w);
  return t.v;
}
__device__ inline f32x4 mfma16(bf16x8 a, bf16x8 b, f32x4 c) {
  return __builtin_amdgcn_mfma_f32_16x16x32_bf16(a, b, c, 0, 0, 0);
}
__device__ inline float sigm(float x) {
  x = fminf(fmaxf(x, -30.f), 30.f);
  return 1.f / (1.f + __expf(-x));
}
__device__ inline float tanh_(float x) {
  x = fminf(fmaxf(x, -15.f), 15.f);
  float e = __expf(-2.f * x);
  return (1.f - e) / (1.f + e);
}

// Group barrier (R10 form — best measured). vmcnt(0) drains all data RMWs
// before arrival (workgroup-release). Monotonic counters, no reset; arrivals
// spread over 8 sub-lines (4 blocks each).
// FAST: arrival + polls are L2-executing RMWs. Poll = 8 lanes x 1 RMW on
// distinct sub-lines, butterfly-summed. !FAST: agent scope, exactly R5.
// Valve: break out after pathological spins (wrong answer, never hang).
template <bool FAST>
__device__ inline void group_bar(unsigned* base, int blkrank, unsigned t) {
  asm volatile("s_waitcnt vmcnt(0)" ::: "memory");
  __syncthreads();
  if (FAST) {
    const unsigned target = t * GRP_BLKS;
    if (threadIdx.x == 0)
      __hip_atomic_fetch_add(base + (blkrank & 7) * 32, 1u, __ATOMIC_RELAXED,
                             __HIP_MEMORY_SCOPE_WORKGROUP);
    if (threadIdx.x < 8) {
      unsigned z = opaque_zero32();
      unsigned spins = 0;
      for (;;) {
        unsigned s = __hip_atomic_fetch_add(base + (int)threadIdx.x * 32, z,
                                            __ATOMIC_RELAXED,
                                            __HIP_MEMORY_SCOPE_WORKGROUP);
        s += __shfl_xor((int)s, 1);
        s += __shfl_xor((int)s, 2);
        s += __shfl_xor((int)s, 4);
        if ((int)(s - target) >= 0) break;
        if (++spins > (1u << 15)) break;   // distress valve
        __builtin_amdgcn_s_sleep(1);
      }
    }
  } else {
    if (threadIdx.x == 0) {
      const int sub = blkrank & 7;
      const unsigned target = t * GRP_BLKS;
      __hip_atomic_fetch_add(base + sub * 32, 1u, __ATOMIC_RELAXED,
                             __HIP_MEMORY_SCOPE_AGENT);
      unsigned s;
      do {
        __builtin_amdgcn_s_sleep(1);
        s = 0;
#pragma unroll
        for (int i = 0; i < 8; ++i)
          s += __hip_atomic_load(base + i * 32, __ATOMIC_RELAXED,
                                 __HIP_MEMORY_SCOPE_AGENT);
      } while ((int)(s - target) < 0);
    }
  }
  __syncthreads();
  asm volatile("" ::: "memory");   // compiler fence: no load hoisting
}

// ---------------------------------------------------------------------------
// RevIN statistics: mean + std (ddof=1) per (batch, channel), two-pass.
// ---------------------------------------------------------------------------
__global__ void stats_kernel(const float* __restrict__ trt,
                             const float* __restrict__ outh,
                             const float* __restrict__ cov,
                             float* __restrict__ stats) {
  int b = blockIdx.x;
  int ch = threadIdx.x;
  if (ch >= 96) return;
  const float* p; int C; float* mdst; float* sdst; int si;
  if (ch < 16)      { p = trt  + (size_t)b * L_ * 16 + ch;        C = 16; mdst = stats + ST_TM; sdst = stats + ST_TSD; si = b * 16 + ch; }
  else if (ch < 32) { p = outh + (size_t)b * L_ * 16 + (ch - 16); C = 16; mdst = stats + ST_OM; sdst = stats + ST_OSD; si = b * 16 + ch - 16; }
  else              { p = cov  + (size_t)b * L_ * 64 + (ch - 32); C = 64; mdst = stats + ST_CM; sdst = stats + ST_CSD; si = b * 64 + ch - 32; }
  float s = 0.f;
  for (int t = 0; t < L_; ++t) s += p[(size_t)t * C];
  float m = s / (float)L_;
  float q = 0.f;
  for (int t = 0; t < L_; ++t) { float d = p[(size_t)t * C] - m; q += d * d; }
  float sd = sqrtf(q / (float)(L_ - 1));
  mdst[si] = m; sdst[si] = sd;
}

// ---------------------------------------------------------------------------
// Normalize + concat -> xn bf16, layout [t][b][c]
// ---------------------------------------------------------------------------
__global__ void norm_kernel(const float* __restrict__ trt,
                            const float* __restrict__ outh,
                            const float* __restrict__ cov,
                            const float* __restrict__ stats,
                            const float* __restrict__ w_t, const float* __restrict__ b_t,
                            const float* __restrict__ w_o, const float* __restrict__ b_o,
                            const float* __restrict__ w_c, const float* __restrict__ b_c,
                            unsigned short* __restrict__ xn) {
  int idx = blockIdx.x * 256 + threadIdx.x;  // < L*B*96
  int c = idx % CI_;
  int tb = idx / CI_;
  int b = tb % B_;
  int t = tb / B_;
  float v, m, sd, w, bb;
  if (c < 16) {
    v = trt[((size_t)b * L_ + t) * 16 + c];
    m = stats[ST_TM + b * 16 + c]; sd = stats[ST_TSD + b * 16 + c];
    w = w_t[c]; bb = b_t[c];
  } else if (c < 32) {
    int cc = c - 16;
    v = outh[((size_t)b * L_ + t) * 16 + cc];
    m = stats[ST_OM + b * 16 + cc]; sd = stats[ST_OSD + b * 16 + cc];
    w = w_o[cc]; bb = b_o[cc];
  } else {
    int cc = c - 32;
    v = cov[((size_t)b * L_ + t) * 64 + cc];
    m = stats[ST_CM + b * 64 + cc]; sd = stats[ST_CSD + b * 64 + cc];
    w = w_c[cc]; bb = b_c[cc];
  }
  xn[idx] = f2bf((v - m) / (sd + EPSR) * w + bb);
}

// ---------------------------------------------------------------------------
// Persistent GRU kernel. 256 blocks x 256 threads = 4 waves = 2 wave-pairs.
// Group g owns batch tile m0 = g*16; idx (0..31):
//   idx<16  -> cell0, u-tile = idx*2+sub;  idx>=16 -> cell1.
// Phase t=1..513: cell0: h0(t)=cell(x_t, h0(t-1));
//                 cell1: h1(t-1)=cell(h0(t-1), h1(t-2)); one group barrier.
// h0 slot index = t & h0mask (h0mask=1023: unique slot per t; =1: ping-pong).
// ---------------------------------------------------------------------------
template <int ROLE, int NGI, int KI, int NGH, int CH0, bool GATES, bool FAST>
__device__ __forceinline__ void wave_run(
    unsigned* barbase, int blkrank, unsigned h0mask,
    float (*exch)[64][4],
    int lane, int u0, int m0,
    const unsigned short* __restrict__ xn,
    unsigned short* __restrict__ ys,
    unsigned short* __restrict__ h0buf,
    const float* __restrict__ WI, const float* __restrict__ WH,
    const float* __restrict__ bi, const float* __restrict__ bh) {
  const int quad = lane >> 4;
  const int l16 = lane & 15;
  const int b = m0 + l16;      // A-fragment row (batch)
  const int urow = u0 + l16;   // weight row within gate block / output column

  bf16x8 BGI[3][NGI > 0 ? NGI : 1];
  bf16x8 BGH[3][NGH > 0 ? NGH : 1];
  if (NGI > 0) {
#pragma unroll
    for (int g = 0; g < 3; ++g)
#pragma unroll
      for (int c = 0; c < NGI; ++c)
        BGI[g][c] = cvt_frag(WI + (size_t)(g * H_ + urow) * KI + 32 * c + quad * 8);
  }
  if (NGH > 0) {
#pragma unroll
    for (int g = 0; g < 3; ++g)
#pragma unroll
      for (int c = 0; c < NGH; ++c)
        BGH[g][c] = cvt_frag(WH + (size_t)(g * H_ + urow) * H_ + 32 * (CH0 + c) + quad * 8);
  }
  float bi_[3] = {0.f, 0.f, 0.f}, bh_[3] = {0.f, 0.f, 0.f};
  if (GATES) {
#pragma unroll
    for (int g = 0; g < 3; ++g) { bi_[g] = bi[g * H_ + urow]; bh_[g] = bh[g * H_ + urow]; }
  }
  // register-carried previous h at (m0+quad*4+r, urow) — this lane wrote it.
  float hp[4] = {0.f, 0.f, 0.f, 0.f};

  for (int t = 1; t <= 513; ++t) {
    const bool active = (ROLE == 0) ? (t <= 512) : (t >= 2);
    f32x4 agi[3], agh[3];
#pragma unroll
    for (int g = 0; g < 3; ++g) {
      agi[g] = (f32x4){0.f, 0.f, 0.f, 0.f};
      agh[g] = (f32x4){0.f, 0.f, 0.f, 0.f};
    }
    if (active) {
      const bool gh_ok = (NGH > 0) && ((ROLE == 0) || (t >= 3));
      bf16x8 ai[NGI > 0 ? NGI : 1];
      bf16x8 ah[NGH > 0 ? NGH : 1];
      // --- issue all A-fragment loads (batched for issue-parallelism) ---
      if (NGI > 0) {
        const unsigned short* Agi = (ROLE == 0)
            ? xn + ((size_t)(t - 1) * B_ + b) * CI_
            : h0buf + (size_t)((t - 1) & h0mask) * B_ * H_ + (size_t)b * H_;
#pragma unroll
        for (int c = 0; c < NGI; ++c) {
          const unsigned short* p = Agi + 32 * c + quad * 8;
          // FAST: plain load — address unique per t, L1 cannot be stale;
          // line sits dirty in local L2 (placed there by the atomic store).
          ai[c] = (ROLE == 0 || FAST) ? load_bf8(p) : load_bf8_coh(p);
        }
      }
      if (gh_ok) {
        const unsigned short* Agh = (ROLE == 0)
            ? h0buf + (size_t)((t - 1) & h0mask) * B_ * H_ + (size_t)b * H_
            : ys + (size_t)(t - 3) * B_ * H_ + (size_t)b * H_;
#pragma unroll
        for (int c = 0; c < NGH; ++c) {
          const unsigned short* p = Agh + 32 * (CH0 + c) + quad * 8;
          ah[c] = FAST ? load_bf8(p) : load_bf8_coh(p);
        }
      }
      // --- MFMAs (compiler inserts the waitcnts) ---
      if (NGI > 0) {
#pragma unroll
        for (int c = 0; c < NGI; ++c) {
          agi[0] = mfma16(ai[c], BGI[0][c], agi[0]);
          agi[1] = mfma16(ai[c], BGI[1][c], agi[1]);
          agi[2] = mfma16(ai[c], BGI[2][c], agi[2]);
        }
      }
      if (gh_ok) {
#pragma unroll
        for (int c = 0; c < NGH; ++c) {
          agh[0] = mfma16(ah[c], BGH[0][c], agh[0]);
          agh[1] = mfma16(ah[c], BGH[1][c], agh[1]);
          agh[2] = mfma16(ah[c], BGH[2][c], agh[2]);
        }
      }
    }
    if (!GATES) {
      // producer wave: publish gh partials to LDS (zeros when inactive)
#pragma unroll
      for (int g = 0; g < 3; ++g)
#pragma unroll
        for (int r = 0; r < 4; ++r) exch[g][lane][r] = agh[g][r];
      __syncthreads();
    } else {
      __syncthreads();
      if (active) {
#pragma unroll
        for (int g = 0; g < 3; ++g)
#pragma unroll
          for (int r = 0; r < 4; ++r) agh[g][r] += exch[g][lane][r];
        unsigned us[4];
#pragma unroll
        for (int r = 0; r < 4; ++r) {
          float rr = sigm(agi[0][r] + bi_[0] + agh[0][r] + bh_[0]);
          float zz = sigm(agi[1][r] + bi_[1] + agh[1][r] + bh_[1]);
          float nn = tanh_(agi[2][r] + bi_[2] + rr * (agh[2][r] + bh_[2]));
          float hv = (1.f - zz) * nn + zz * hp[r];
          hp[r] = hv;
          us[r] = f2bf(hv);
        }
        // pack 2 bf16 along u (adjacent l16 lanes) -> u32 stores.
        unsigned sh0 = (unsigned)__shfl_xor((int)us[0], 1);
        unsigned sh1 = (unsigned)__shfl_xor((int)us[1], 1);
        unsigned sh2 = (unsigned)__shfl_xor((int)us[2], 1);
        unsigned sh3 = (unsigned)__shfl_xor((int)us[3], 1);
        bool odd = (l16 & 1) != 0;
        unsigned ownA = odd ? us[2] : us[0];
        unsigned prtA = odd ? sh2 : sh0;
        unsigned ownB = odd ? us[3] : us[1];
        unsigned prtB = odd ? sh3 : sh1;
        unsigned pkA = odd ? ((prtA & 0xffffu) | (ownA << 16))
                           : ((ownA & 0xffffu) | (prtA << 16));
        unsigned pkB = odd ? ((prtB & 0xffffu) | (ownB << 16))
                           : ((ownB & 0xffffu) | (prtB << 16));
        int rA = odd ? 2 : 0;
        unsigned short* outp = (ROLE == 0)
            ? h0buf + (size_t)(t & h0mask) * B_ * H_
            : ys + (size_t)(t - 2) * B_ * H_;
        unsigned* dst = (unsigned*)outp;
        size_t idxA = (size_t)(m0 + quad * 4 + rA) * (H_ / 2)
                      + ((u0 + (l16 & ~1)) >> 1);
        if (FAST) {
          // L2-allocating RMW stores: line lands dirty in the local L2.
          store_u32_l2rmw(dst + idxA, pkA);
          store_u32_l2rmw(dst + idxA + (H_ / 2), pkB);
        } else {
          __hip_atomic_store(dst + idxA, pkA, __ATOMIC_RELAXED,
                             __HIP_MEMORY_SCOPE_AGENT);
          __hip_atomic_store(dst + idxA + (H_ / 2), pkB, __ATOMIC_RELAXED,
                             __HIP_MEMORY_SCOPE_AGENT);
        }
      }
    }
    group_bar<FAST>(barbase, blkrank, (unsigned)t);
  }
}

template <bool FAST>
__device__ __forceinline__ void run_roles(
    int grp, int idx, int wave, int lane, unsigned h0mask,
    float (*exchall)[3][64][4], unsigned* barbase,
    const unsigned short* __restrict__ xn,
    unsigned short* __restrict__ ys,
    unsigned short* __restrict__ h0buf,
    const float* __restrict__ Wih0, const float* __restrict__ Whh0,
    const float* __restrict__ bih0, const float* __restrict__ bhh0,
    const float* __restrict__ Wih1, const float* __restrict__ Whh1,
    const float* __restrict__ bih1, const float* __restrict__ bhh1) {
  const int m0 = grp * 16;
  const int sub = wave >> 1;   // which wave-pair in this block
  const int wr = wave & 1;     // 0 = GATES consumer, 1 = producer
  float (*exch)[64][4] = exchall[sub];

  if (idx < 16) {
    int u0 = (idx * 2 + sub) * 16;
    if (wr == 0)
      wave_run<0, 3, CI_, 8, 0, true, FAST>(barbase, idx, h0mask, exch, lane, u0, m0,
                                            xn, ys, h0buf, Wih0, Whh0, bih0, bhh0);
    else
      wave_run<0, 0, CI_, 8, 8, false, FAST>(barbase, idx, h0mask, exch, lane, u0, m0,
                                             xn, ys, h0buf, Wih0, Whh0, bih0, bhh0);
  } else {
    int u0 = ((idx - 16) * 2 + sub) * 16;
    if (wr == 0)
      wave_run<1, 16, H_, 0, 0, true, FAST>(barbase, idx, h0mask, exch, lane, u0, m0,
                                            xn, ys, h0buf, Wih1, Whh1, bih1, bhh1);
    else
      wave_run<1, 0, H_, 16, 0, false, FAST>(barbase, idx, h0mask, exch, lane, u0, m0,
                                             xn, ys, h0buf, Wih1, Whh1, bih1, bhh1);
  }
}

__launch_bounds__(256, 1)
__global__ void rnn_kernel(const unsigned short* __restrict__ xn,
                           unsigned short* __restrict__ ys,
                           unsigned short* __restrict__ h0buf,
                           unsigned* __restrict__ bar,
                           unsigned* __restrict__ xcdtab,
                           unsigned h0mask, int allowfast,
                           const float* __restrict__ Wih0, const float* __restrict__ Whh0,
                           const float* __restrict__ bih0, const float* __restrict__ bhh0,
                           const float* __restrict__ Wih1, const float* __restrict__ Whh1,
                           const float* __restrict__ bih1, const float* __restrict__ bhh1) {
  __shared__ float exch[2][3][64][4];
  __shared__ unsigned s_x[256];

  // ---- prologue: XCD roster (one-time, agent scope, model-correct fences) ----
  int xcd;
  asm volatile("s_getreg_b32 %0, hwreg(HW_REG_XCC_ID)" : "=s"(xcd));
  xcd &= 7;
  bool sawall = true;
  if (threadIdx.x == 0) {
    __hip_atomic_store(&xcdtab[blockIdx.x], (unsigned)xcd, __ATOMIC_RELAXED,
                       __HIP_MEMORY_SCOPE_AGENT);
    __threadfence();   // release: roster entry at coherence point before arrival
    __hip_atomic_fetch_add(&xcdtab[256], 1u, __ATOMIC_RELAXED,
                           __HIP_MEMORY_SCOPE_AGENT);
    unsigned got, spins = 0;
    do {
      __builtin_amdgcn_s_sleep(8);
      got = __hip_atomic_load(&xcdtab[256], __ATOMIC_RELAXED,
                              __HIP_MEMORY_SCOPE_AGENT);
      if (++spins > (1u << 16)) break;   // distress valve
    } while (got < 256u);
    sawall = (got >= 256u);
    __threadfence();   // acquire: subsequent roster reads see all entries
    s_x[0] = sawall ? 1u : 0u;
  }
  __syncthreads();
  sawall = (s_x[0] != 0u);
  __syncthreads();
  s_x[threadIdx.x] = __hip_atomic_load(&xcdtab[threadIdx.x], __ATOMIC_RELAXED,
                                       __HIP_MEMORY_SCOPE_AGENT);
  __syncthreads();
  if (threadIdx.x == 0) {
    int cnt[8] = {0, 0, 0, 0, 0, 0, 0, 0};
    int rank = 0;
    for (int j = 0; j < 256; ++j) {
      unsigned x = s_x[j] & 7u;
      cnt[x]++;
      if (j < (int)blockIdx.x && x == (unsigned)xcd) rank++;
    }
    bool ok = sawall;
#pragma unroll
    for (int k = 0; k < 8; ++k) ok = ok && (cnt[k] == 32);
    s_x[0] = ok ? 1u : 0u;
    s_x[1] = (unsigned)rank;
  }
  __syncthreads();
  const bool fastp = (s_x[0] != 0u) && (allowfast != 0);
  const int ridx = (int)s_x[1];

  const int wave = threadIdx.x >> 6;
  const int lane = threadIdx.x & 63;

  if (fastp) {
    const int grp = xcd;                 // group = physical XCD -> L2-local
    run_roles<true>(grp, ridx, wave, lane, h0mask, exch, bar + grp * (64 * 32),
                    xn, ys, h0buf, Wih0, Whh0, bih0, bhh0,
                    Wih1, Whh1, bih1, bhh1);
  } else {
    const int grp = (int)(blockIdx.x & 7);
    const int idx = (int)(blockIdx.x >> 3);
    run_roles<false>(grp, idx, wave, lane, h0mask, exch, bar + grp * (64 * 32),
                     xn, ys, h0buf, Wih0, Whh0, bih0, bhh0,
                     Wih1, Whh1, bih1, bhh1);
  }
}

// ---------------------------------------------------------------------------
// Output projection (65536 x 80, K=512) + inverse RevIN, MFMA.
// grid = 512 m-chunks * 5 n-tiles = 2560 blocks x 64 threads (1 wave).
// ---------------------------------------------------------------------------
__global__ void out_kernel(const unsigned short* __restrict__ ys,
                           const float* __restrict__ Wout, const float* __restrict__ bout,
                           const float* __restrict__ w_o, const float* __restrict__ b_o,
                           const float* __restrict__ w_c, const float* __restrict__ b_c,
                           const float* __restrict__ stats,
                           float* __restrict__ dout) {
  int lane = threadIdx.x;
  int quad = lane >> 4, l16 = lane & 15;
  int nb = blockIdx.x % 5, mc = blockIdx.x / 5;
  int ch = nb * 16 + l16;

  bf16x8 BW[16];
#pragma unroll
  for (int c = 0; c < 16; ++c)
    BW[c] = cvt_frag(Wout + (size_t)ch * 512 + 32 * c + quad * 8);
  float bo = bout[ch];
  float rb, rw; const float* mm; const float* ss; int cs, cidx;
  if (ch < 16) { rb = b_o[ch]; rw = w_o[ch]; mm = stats + ST_OM; ss = stats + ST_OSD; cs = 16; cidx = ch; }
  else         { rb = b_c[ch - 16]; rw = w_c[ch - 16]; mm = stats + ST_CM; ss = stats + ST_CSD; cs = 64; cidx = ch - 16; }

  for (int i = 0; i < 8; ++i) {
    int mt = mc * 8 + i;
    const unsigned short* A = ys + (size_t)(mt * 16 + l16) * 512;
    f32x4 acc = {0.f, 0.f, 0.f, 0.f};
#pragma unroll
    for (int c = 0; c < 16; ++c)
      acc = mfma16(load_bf8(A + 32 * c + quad * 8), BW[c], acc);
#pragma unroll
    for (int r = 0; r < 4; ++r) {
      int rr = mt * 16 + quad * 4 + r;
      int t = rr >> 7;
      int b = rr & 127;
      float m = mm[b * cs + cidx], sd = ss[b * cs + cidx];
      float v = (acc[r] + bo - rb) / rw * (sd + EPSR) + m;
      size_t off = (ch < 16)
          ? ((size_t)b * 8192 + (size_t)t * 16 + ch)
          : ((size_t)1048576 + (size_t)b * 32768 + (size_t)t * 64 + (ch - 16));
      dout[off] = v;
    }
  }
}

// ---------------------------------------------------------------------------
extern "C" void kernel_launch(void* const* d_in, const int* in_sizes, int n_in,
                              void* d_out, int out_size, void* d_ws, size_t ws_size,
                              hipStream_t stream) {
  const float* cov  = (const float*)d_in[0];
  const float* trt  = (const float*)d_in[1];
  const float* outh = (const float*)d_in[2];
  const float* Wih0 = (const float*)d_in[3];
  const float* Whh0 = (const float*)d_in[4];
  const float* bih0 = (const float*)d_in[5];
  const float* bhh0 = (const float*)d_in[6];
  const float* Wih1 = (const float*)d_in[7];
  const float* Whh1 = (const float*)d_in[8];
  const float* bih1 = (const float*)d_in[9];
  const float* bhh1 = (const float*)d_in[10];
  const float* Wout = (const float*)d_in[11];
  const float* bout = (const float*)d_in[12];
  const float* w_t  = (const float*)d_in[13];
  const float* b_t  = (const float*)d_in[14];
  const float* w_o  = (const float*)d_in[15];
  const float* b_o  = (const float*)d_in[16];
  const float* w_c  = (const float*)d_in[17];
  const float* b_c  = (const float*)d_in[18];

  char* ws = (char*)d_ws;
  unsigned short* xn = (unsigned short*)(ws + XN_OFF);
  unsigned short* ys = (unsigned short*)(ws + YS_OFF);

  // Unique-h0 layout if workspace allows; else compact (R5) layout.
  const size_t u_h0   = YS_OFF + YS_BYTES;
  const size_t u_bar  = u_h0 + H0U_BYTES;
  const size_t u_xcdt = u_bar + BAR_BYTES;
  const size_t u_st   = u_xcdt + XCDT_BYTES;
  const size_t u_need = u_st + STATS_BYTES;
  const bool uniq = (ws_size >= u_need);

  unsigned short* h0;
  unsigned *bar, *xcdt;
  float* stats;
  unsigned h0mask;
  int allowfast;
  if (uniq) {
    h0    = (unsigned short*)(ws + u_h0);
    bar   = (unsigned*)(ws + u_bar);
    xcdt  = (unsigned*)(ws + u_xcdt);
    stats = (float*)(ws + u_st);
    h0mask = 1023u;        // slot = t (t <= 513)
    allowfast = 1;
    // ws re-poisoned to 0xAA before every launch: zero h0 slot 0 + barriers
    // + roster. (Slots 1..512 are written before read.)
    (void)hipMemsetAsync((void*)(ws + u_h0), 0, H0SLOT_BYTES, stream);
    (void)hipMemsetAsync((void*)(ws + u_bar), 0, BAR_BYTES + XCDT_BYTES, stream);
  } else {
    h0    = (unsigned short*)(ws + H0_OFF);
    bar   = (unsigned*)(ws + H0_OFF + H0_BYTES);
    xcdt  = (unsigned*)(ws + H0_OFF + H0_BYTES + BAR_BYTES);
    stats = (float*)(ws + H0_OFF + H0_BYTES + BAR_BYTES + XCDT_BYTES);
    h0mask = 1u;           // ping-pong (agent-scope fallback only)
    allowfast = 0;
    (void)hipMemsetAsync((void*)(ws + H0_OFF), 0,
                         H0_BYTES + BAR_BYTES + XCDT_BYTES, stream);
  }

  stats_kernel<<<128, 128, 0, stream>>>(trt, outh, cov, stats);
  norm_kernel<<<(L_ * B_ * CI_) / 256, 256, 0, stream>>>(
      trt, outh, cov, stats, w_t, b_t, w_o, b_o, w_c, b_c, xn);

  rnn_kernel<<<256, 256, 0, stream>>>(xn, ys, h0, bar, xcdt, h0mask, allowfast,
                                      Wih0, Whh0, bih0, bhh0,
                                      Wih1, Whh1, bih1, bhh1);

  out_kernel<<<2560, 64, 0, stream>>>(ys, Wout, bout, w_o, b_o, w_c, b_c,
                                      stats, (float*)d_out);
}

// Round 8
// 2572.224 us; speedup vs baseline: 1.1665x; 1.0246x over previous
//
#include <hip/hip_runtime.h>

// ---------------------------------------------------------------------------
// GNet: RevIN -> 2-layer GRU (B=128, L=512, H=512, I=96) -> proj -> RevIN^-1
// Persistent kernel, 256 blocks x 256 thr, weights in VGPRs as bf16 MFMA
// B-frags, 8 sync groups (one per XCD when roster verifies).
// Ledger:
// R5 3234us PASS: agent-scope exchange, joint 32-block barrier.
// R9: nt stores stream to HBM (dead); roster CONFIRMED 32 blocks/XCD.
// R10 ~2650us: unique-slot h0 + plain ops (no stale-L1 possible). PROVEN.
// R11 ~2910us: leader/GO barrier REGRESSED -> barrier not dominant.
// R12 ~2480us: atomicExch data stores (small win). FETCH pinned ~111MB across
//    plain/atomic stores => gfx950 XCD-L2 does NOT retain stores for later
//    readers in ANY flavor; exchange is structurally MALL-resident. Fabric-
//    latency lever exhausted.
// R13: SYNC DECOUPLING. Dependency graph: cell0 depends only on itself;
//    cell1 consumes h0(t-1) (1-phase slack) and own ys(t-3) (3-phase slack).
//    The joint barrier made the group advance at max(chains)+coupling.
//    Now: cell0 = private 16-block barrier (lines 0..7) + bumps a mirror
//    progress set (lines 8..15); never waits cell1. cell1 = private 16-block
//    barrier (lines 16..23) AND mirror>=16t, one combined 16-lane poll.
//    Unique slots => any drift is harmless (no reuse). Monotonic counters,
//    valves on all spins. Fallback = exact joint R5 barrier. Guideline 16.
// ---------------------------------------------------------------------------

typedef __attribute__((ext_vector_type(8))) __bf16 bf16x8;
typedef __attribute__((ext_vector_type(4))) float  f32x4;

constexpr int B_  = 128;
constexpr int L_  = 512;
constexpr int H_  = 512;
constexpr int CI_ = 96;    // 16 treat + 16 outcome + 64 covariate
constexpr float EPSR = 1e-5f;
constexpr unsigned GRP_BLKS = 32;   // blocks per sync group (fallback joint)
constexpr unsigned ROLE_BLKS = 16;  // blocks per role (fast split)

// ---- compact (fallback) ws layout ----
constexpr size_t XN_OFF = 0;                                   // bf16 [L][B][96]
constexpr size_t XN_BYTES = (size_t)L_ * B_ * CI_ * 2;
constexpr size_t YS_OFF = XN_OFF + XN_BYTES;                   // bf16 [L][B][H]
constexpr size_t YS_BYTES = (size_t)L_ * B_ * H_ * 2;
constexpr size_t H0_OFF = YS_OFF + YS_BYTES;                   // bf16 [2][B][H]
constexpr size_t H0_BYTES = (size_t)2 * B_ * H_ * 2;
// barrier: per group 64 lines x 128B. FAST: 0..7 cell0 arrivals, 8..15 cell0
// progress mirror, 16..23 cell1 arrivals. SLOW(joint): lines 0..7.
constexpr size_t BAR_BYTES = 8 * 64 * 128;                     // 64 KB
constexpr size_t XCDT_BYTES = 2048;                            // 256 ids + ctr
constexpr size_t STATS_BYTES = 24576 * 4;
// ---- unique-h0 region ----
constexpr size_t H0SLOT_BYTES = (size_t)B_ * H_ * 2;           // 128 KB
constexpr size_t H0U_SLOTS = 513;
constexpr size_t H0U_BYTES = H0U_SLOTS * H0SLOT_BYTES;         // ~67 MB
// stats float offsets
constexpr int ST_TM = 0, ST_TSD = 2048, ST_OM = 4096, ST_OSD = 6144,
              ST_CM = 8192, ST_CSD = 16384;  // total 24576 floats

__device__ inline unsigned short f2bf(float f) {
  unsigned u = __builtin_bit_cast(unsigned, f);
  u += 0x7fffu + ((u >> 16) & 1u);
  return (unsigned short)(u >> 16);
}

union U16x8 { uint4 u4; unsigned long long q[2]; unsigned short s[8]; bf16x8 v; };

__device__ inline bf16x8 load_bf8(const unsigned short* p) {   // plain cached
  U16x8 t; t.u4 = *(const uint4*)p; return t.v;
}
// Agent-coherent (sc1, IF-level) fragment load: 2 x u64 relaxed. (slow path)
__device__ inline bf16x8 load_bf8_coh(const unsigned short* p) {
  U16x8 t;
  const unsigned long long* q = (const unsigned long long*)p;
  t.q[0] = __hip_atomic_load(q + 0, __ATOMIC_RELAXED, __HIP_MEMORY_SCOPE_AGENT);
  t.q[1] = __hip_atomic_load(q + 1, __ATOMIC_RELAXED, __HIP_MEMORY_SCOPE_AGENT);
  return t.v;
}
// Optimizer-opaque zero (SGPR) — keeps poll RMWs as real RMWs.
__device__ __forceinline__ unsigned opaque_zero32() {
  unsigned z;
  asm("s_mov_b32 %0, 0" : "=s"(z));
  return z;
}
// Data store via non-returning atomic swap (R12 — best measured).
__device__ __forceinline__ void store_u32_rmw(unsigned* p, unsigned v) {
  (void)__hip_atomic_exchange(p, v, __ATOMIC_RELAXED,
                              __HIP_MEMORY_SCOPE_WORKGROUP);
}

__device__ inline bf16x8 cvt_frag(const float* p) {  // 8 consecutive fp32 -> bf16x8
  U16x8 t;
  float4 a = *(const float4*)p;
  float4 b = *(const float4*)(p + 4);
  t.s[0] = f2bf(a.x); t.s[1] = f2bf(a.y); t.s[2] = f2bf(a.z); t.s[3] = f2bf(a.w);
  t.s[4] = f2bf(b.x); t.s[5] = f2bf(b.y); t.s[6] = f2bf(b.z); t.s[7] = f2bf(b.w);
  return t.v;
}
__device__ inline f32x4 mfma16(bf16x8 a, bf16x8 b, f32x4 c) {
  return __builtin_amdgcn_mfma_f32_16x16x32_bf16(a, b, c, 0, 0, 0);
}
__device__ inline float sigm(float x) {
  x = fminf(fmaxf(x, -30.f), 30.f);
  return 1.f / (1.f + __expf(-x));
}
__device__ inline float tanh_(float x) {
  x = fminf(fmaxf(x, -15.f), 15.f);
  float e = __expf(-2.f * x);
  return (1.f - e) / (1.f + e);
}

// Role-split group barrier (FAST) / joint agent barrier (!FAST).
// vmcnt(0) drains all data stores before arrival (release). Monotonic
// counters, no reset. Valves: break out (wrong answer, never hang).
// FAST ROLE 0 (cell0): arrive line rank&7 (region 0..7) + bump mirror line
//   8+(rank&7); 8-lane RMW-poll region0 sum >= 16t. Never waits cell1.
// FAST ROLE 1 (cell1): arrive line 16+(rank&7); 16-lane combined poll:
//   lanes 0..7 sum region 16..23 (own, >=16t), lanes 8..15 sum mirror
//   8..15 (cell0 progress, >=16t); ballot-joined.
template <bool FAST, int ROLE>
__device__ inline void group_bar(unsigned* base, int rank, unsigned t) {
  asm volatile("s_waitcnt vmcnt(0)" ::: "memory");
  __syncthreads();
  if (FAST) {
    const unsigned T16 = t * ROLE_BLKS;
    if (ROLE == 0) {
      if (threadIdx.x == 0) {
        __hip_atomic_fetch_add(base + (rank & 7) * 32, 1u, __ATOMIC_RELAXED,
                               __HIP_MEMORY_SCOPE_WORKGROUP);
        __hip_atomic_fetch_add(base + (8 + (rank & 7)) * 32, 1u,
                               __ATOMIC_RELAXED, __HIP_MEMORY_SCOPE_WORKGROUP);
      }
      if (threadIdx.x < 8) {
        unsigned z = opaque_zero32();
        unsigned spins = 0;
        for (;;) {
          unsigned s = __hip_atomic_fetch_add(base + (int)threadIdx.x * 32, z,
                                              __ATOMIC_RELAXED,
                                              __HIP_MEMORY_SCOPE_WORKGROUP);
          s += __shfl_xor((int)s, 1);
          s += __shfl_xor((int)s, 2);
          s += __shfl_xor((int)s, 4);
          if ((int)(s - T16) >= 0) break;
          if (++spins > (1u << 15)) break;   // distress valve
          __builtin_amdgcn_s_sleep(1);
        }
      }
    } else {
      if (threadIdx.x == 0)
        __hip_atomic_fetch_add(base + (16 + (rank & 7)) * 32, 1u,
                               __ATOMIC_RELAXED, __HIP_MEMORY_SCOPE_WORKGROUP);
      if (threadIdx.x < 16) {
        // lanes 0..7 -> own arrivals (lines 16..23); lanes 8..15 -> mirror
        // (lines 8..15). shfl_xor 1/2/4 sums stay within each 8-lane group.
        const int line = (threadIdx.x < 8) ? (16 + (int)threadIdx.x)
                                           : (int)threadIdx.x;
        unsigned z = opaque_zero32();
        unsigned spins = 0;
        for (;;) {
          unsigned s = __hip_atomic_fetch_add(base + line * 32, z,
                                              __ATOMIC_RELAXED,
                                              __HIP_MEMORY_SCOPE_WORKGROUP);
          s += __shfl_xor((int)s, 1);
          s += __shfl_xor((int)s, 2);
          s += __shfl_xor((int)s, 4);
          bool ok = (int)(s - T16) >= 0;
          unsigned long long bal = __ballot(ok);
          if ((bal & 0xFFFFull) == 0xFFFFull) break;
          if (++spins > (1u << 15)) break;   // distress valve
          __builtin_amdgcn_s_sleep(1);
        }
      }
    }
  } else {
    if (threadIdx.x == 0) {
      const int sub = rank & 7;   // (idx-16)&7 == idx&7: same mapping as R5
      const unsigned target = t * GRP_BLKS;
      __hip_atomic_fetch_add(base + sub * 32, 1u, __ATOMIC_RELAXED,
                             __HIP_MEMORY_SCOPE_AGENT);
      unsigned s;
      do {
        __builtin_amdgcn_s_sleep(1);
        s = 0;
#pragma unroll
        for (int i = 0; i < 8; ++i)
          s += __hip_atomic_load(base + i * 32, __ATOMIC_RELAXED,
                                 __HIP_MEMORY_SCOPE_AGENT);
      } while ((int)(s - target) < 0);
    }
  }
  __syncthreads();
  asm volatile("" ::: "memory");   // compiler fence: no load hoisting
}

// ---------------------------------------------------------------------------
// RevIN statistics: mean + std (ddof=1) per (batch, channel), two-pass.
// ---------------------------------------------------------------------------
__global__ void stats_kernel(const float* __restrict__ trt,
                             const float* __restrict__ outh,
                             const float* __restrict__ cov,
                             float* __restrict__ stats) {
  int b = blockIdx.x;
  int ch = threadIdx.x;
  if (ch >= 96) return;
  const float* p; int C; float* mdst; float* sdst; int si;
  if (ch < 16)      { p = trt  + (size_t)b * L_ * 16 + ch;        C = 16; mdst = stats + ST_TM; sdst = stats + ST_TSD; si = b * 16 + ch; }
  else if (ch < 32) { p = outh + (size_t)b * L_ * 16 + (ch - 16); C = 16; mdst = stats + ST_OM; sdst = stats + ST_OSD; si = b * 16 + ch - 16; }
  else              { p = cov  + (size_t)b * L_ * 64 + (ch - 32); C = 64; mdst = stats + ST_CM; sdst = stats + ST_CSD; si = b * 64 + ch - 32; }
  float s = 0.f;
  for (int t = 0; t < L_; ++t) s += p[(size_t)t * C];
  float m = s / (float)L_;
  float q = 0.f;
  for (int t = 0; t < L_; ++t) { float d = p[(size_t)t * C] - m; q += d * d; }
  float sd = sqrtf(q / (float)(L_ - 1));
  mdst[si] = m; sdst[si] = sd;
}

// ---------------------------------------------------------------------------
// Normalize + concat -> xn bf16, layout [t][b][c]
// ---------------------------------------------------------------------------
__global__ void norm_kernel(const float* __restrict__ trt,
                            const float* __restrict__ outh,
                            const float* __restrict__ cov,
                            const float* __restrict__ stats,
                            const float* __restrict__ w_t, const float* __restrict__ b_t,
                            const float* __restrict__ w_o, const float* __restrict__ b_o,
                            const float* __restrict__ w_c, const float* __restrict__ b_c,
                            unsigned short* __restrict__ xn) {
  int idx = blockIdx.x * 256 + threadIdx.x;  // < L*B*96
  int c = idx % CI_;
  int tb = idx / CI_;
  int b = tb % B_;
  int t = tb / B_;
  float v, m, sd, w, bb;
  if (c < 16) {
    v = trt[((size_t)b * L_ + t) * 16 + c];
    m = stats[ST_TM + b * 16 + c]; sd = stats[ST_TSD + b * 16 + c];
    w = w_t[c]; bb = b_t[c];
  } else if (c < 32) {
    int cc = c - 16;
    v = outh[((size_t)b * L_ + t) * 16 + cc];
    m = stats[ST_OM + b * 16 + cc]; sd = stats[ST_OSD + b * 16 + cc];
    w = w_o[cc]; bb = b_o[cc];
  } else {
    int cc = c - 32;
    v = cov[((size_t)b * L_ + t) * 64 + cc];
    m = stats[ST_CM + b * 64 + cc]; sd = stats[ST_CSD + b * 64 + cc];
    w = w_c[cc]; bb = b_c[cc];
  }
  xn[idx] = f2bf((v - m) / (sd + EPSR) * w + bb);
}

// ---------------------------------------------------------------------------
// Persistent GRU kernel. 256 blocks x 256 threads = 4 waves = 2 wave-pairs.
// Group g owns batch tile m0 = g*16; idx (0..31):
//   idx<16  -> cell0 (rank=idx), u-tile = idx*2+sub;
//   idx>=16 -> cell1 (rank=idx-16).
// Phase t=1..513: cell0: h0(t)=cell(x_t, h0(t-1));
//                 cell1: h1(t-1)=cell(h0(t-1), h1(t-2)).
// FAST sync: cell0 16-barrier (+mirror); cell1 16-barrier AND mirror>=16t.
// h0 slot index = t & h0mask (h0mask=1023: unique slot per t; =1: ping-pong).
// ---------------------------------------------------------------------------
template <int ROLE, int NGI, int KI, int NGH, int CH0, bool GATES, bool FAST>
__device__ __forceinline__ void wave_run(
    unsigned* barbase, int rank, unsigned h0mask,
    float (*exch)[64][4],
    int lane, int u0, int m0,
    const unsigned short* __restrict__ xn,
    unsigned short* __restrict__ ys,
    unsigned short* __restrict__ h0buf,
    const float* __restrict__ WI, const float* __restrict__ WH,
    const float* __restrict__ bi, const float* __restrict__ bh) {
  const int quad = lane >> 4;
  const int l16 = lane & 15;
  const int b = m0 + l16;      // A-fragment row (batch)
  const int urow = u0 + l16;   // weight row within gate block / output column

  bf16x8 BGI[3][NGI > 0 ? NGI : 1];
  bf16x8 BGH[3][NGH > 0 ? NGH : 1];
  if (NGI > 0) {
#pragma unroll
    for (int g = 0; g < 3; ++g)
#pragma unroll
      for (int c = 0; c < NGI; ++c)
        BGI[g][c] = cvt_frag(WI + (size_t)(g * H_ + urow) * KI + 32 * c + quad * 8);
  }
  if (NGH > 0) {
#pragma unroll
    for (int g = 0; g < 3; ++g)
#pragma unroll
      for (int c = 0; c < NGH; ++c)
        BGH[g][c] = cvt_frag(WH + (size_t)(g * H_ + urow) * H_ + 32 * (CH0 + c) + quad * 8);
  }
  float bi_[3] = {0.f, 0.f, 0.f}, bh_[3] = {0.f, 0.f, 0.f};
  if (GATES) {
#pragma unroll
    for (int g = 0; g < 3; ++g) { bi_[g] = bi[g * H_ + urow]; bh_[g] = bh[g * H_ + urow]; }
  }
  // register-carried previous h at (m0+quad*4+r, urow) — this lane wrote it.
  float hp[4] = {0.f, 0.f, 0.f, 0.f};

  for (int t = 1; t <= 513; ++t) {
    const bool active = (ROLE == 0) ? (t <= 512) : (t >= 2);
    f32x4 agi[3], agh[3];
#pragma unroll
    for (int g = 0; g < 3; ++g) {
      agi[g] = (f32x4){0.f, 0.f, 0.f, 0.f};
      agh[g] = (f32x4){0.f, 0.f, 0.f, 0.f};
    }
    if (active) {
      const bool gh_ok = (NGH > 0) && ((ROLE == 0) || (t >= 3));
      bf16x8 ai[NGI > 0 ? NGI : 1];
      bf16x8 ah[NGH > 0 ? NGH : 1];
      // --- issue all A-fragment loads (batched for issue-parallelism) ---
      if (NGI > 0) {
        const unsigned short* Agi = (ROLE == 0)
            ? xn + ((size_t)(t - 1) * B_ + b) * CI_
            : h0buf + (size_t)((t - 1) & h0mask) * B_ * H_ + (size_t)b * H_;
#pragma unroll
        for (int c = 0; c < NGI; ++c) {
          const unsigned short* p = Agi + 32 * c + quad * 8;
          // FAST: plain load — address unique per t, L1 cannot be stale.
          ai[c] = (ROLE == 0 || FAST) ? load_bf8(p) : load_bf8_coh(p);
        }
      }
      if (gh_ok) {
        const unsigned short* Agh = (ROLE == 0)
            ? h0buf + (size_t)((t - 1) & h0mask) * B_ * H_ + (size_t)b * H_
            : ys + (size_t)(t - 3) * B_ * H_ + (size_t)b * H_;
#pragma unroll
        for (int c = 0; c < NGH; ++c) {
          const unsigned short* p = Agh + 32 * (CH0 + c) + quad * 8;
          ah[c] = FAST ? load_bf8(p) : load_bf8_coh(p);
        }
      }
      // --- MFMAs (compiler inserts the waitcnts) ---
      if (NGI > 0) {
#pragma unroll
        for (int c = 0; c < NGI; ++c) {
          agi[0] = mfma16(ai[c], BGI[0][c], agi[0]);
          agi[1] = mfma16(ai[c], BGI[1][c], agi[1]);
          agi[2] = mfma16(ai[c], BGI[2][c], agi[2]);
        }
      }
      if (gh_ok) {
#pragma unroll
        for (int c = 0; c < NGH; ++c) {
          agh[0] = mfma16(ah[c], BGH[0][c], agh[0]);
          agh[1] = mfma16(ah[c], BGH[1][c], agh[1]);
          agh[2] = mfma16(ah[c], BGH[2][c], agh[2]);
        }
      }
    }
    if (!GATES) {
      // producer wave: publish gh partials to LDS (zeros when inactive)
#pragma unroll
      for (int g = 0; g < 3; ++g)
#pragma unroll
        for (int r = 0; r < 4; ++r) exch[g][lane][r] = agh[g][r];
      __syncthreads();
    } else {
      __syncthreads();
      if (active) {
#pragma unroll
        for (int g = 0; g < 3; ++g)
#pragma unroll
          for (int r = 0; r < 4; ++r) agh[g][r] += exch[g][lane][r];
        unsigned us[4];
#pragma unroll
        for (int r = 0; r < 4; ++r) {
          float rr = sigm(agi[0][r] + bi_[0] + agh[0][r] + bh_[0]);
          float zz = sigm(agi[1][r] + bi_[1] + agh[1][r] + bh_[1]);
          float nn = tanh_(agi[2][r] + bi_[2] + rr * (agh[2][r] + bh_[2]));
          float hv = (1.f - zz) * nn + zz * hp[r];
          hp[r] = hv;
          us[r] = f2bf(hv);
        }
        // pack 2 bf16 along u (adjacent l16 lanes) -> u32 stores.
        unsigned sh0 = (unsigned)__shfl_xor((int)us[0], 1);
        unsigned sh1 = (unsigned)__shfl_xor((int)us[1], 1);
        unsigned sh2 = (unsigned)__shfl_xor((int)us[2], 1);
        unsigned sh3 = (unsigned)__shfl_xor((int)us[3], 1);
        bool odd = (l16 & 1) != 0;
        unsigned ownA = odd ? us[2] : us[0];
        unsigned prtA = odd ? sh2 : sh0;
        unsigned ownB = odd ? us[3] : us[1];
        unsigned prtB = odd ? sh3 : sh1;
        unsigned pkA = odd ? ((prtA & 0xffffu) | (ownA << 16))
                           : ((ownA & 0xffffu) | (prtA << 16));
        unsigned pkB = odd ? ((prtB & 0xffffu) | (ownB << 16))
                           : ((ownB & 0xffffu) | (prtB << 16));
        int rA = odd ? 2 : 0;
        unsigned short* outp = (ROLE == 0)
            ? h0buf + (size_t)(t & h0mask) * B_ * H_
            : ys + (size_t)(t - 2) * B_ * H_;
        unsigned* dst = (unsigned*)outp;
        size_t idxA = (size_t)(m0 + quad * 4 + rA) * (H_ / 2)
                      + ((u0 + (l16 & ~1)) >> 1);
        if (FAST) {
          store_u32_rmw(dst + idxA, pkA);
          store_u32_rmw(dst + idxA + (H_ / 2), pkB);
        } else {
          __hip_atomic_store(dst + idxA, pkA, __ATOMIC_RELAXED,
                             __HIP_MEMORY_SCOPE_AGENT);
          __hip_atomic_store(dst + idxA + (H_ / 2), pkB, __ATOMIC_RELAXED,
                             __HIP_MEMORY_SCOPE_AGENT);
        }
      }
    }
    group_bar<FAST, ROLE>(barbase, rank, (unsigned)t);
  }
}

template <bool FAST>
__device__ __forceinline__ void run_roles(
    int grp, int idx, int wave, int lane, unsigned h0mask,
    float (*exchall)[3][64][4], unsigned* barbase,
    const unsigned short* __restrict__ xn,
    unsigned short* __restrict__ ys,
    unsigned short* __restrict__ h0buf,
    const float* __restrict__ Wih0, const float* __restrict__ Whh0,
    const float* __restrict__ bih0, const float* __restrict__ bhh0,
    const float* __restrict__ Wih1, const float* __restrict__ Whh1,
    const float* __restrict__ bih1, const float* __restrict__ bhh1) {
  const int m0 = grp * 16;
  const int sub = wave >> 1;   // which wave-pair in this block
  const int wr = wave & 1;     // 0 = GATES consumer, 1 = producer
  float (*exch)[64][4] = exchall[sub];

  if (idx < 16) {
    int u0 = (idx * 2 + sub) * 16;
    if (wr == 0)
      wave_run<0, 3, CI_, 8, 0, true, FAST>(barbase, idx, h0mask, exch, lane, u0, m0,
                                            xn, ys, h0buf, Wih0, Whh0, bih0, bhh0);
    else
      wave_run<0, 0, CI_, 8, 8, false, FAST>(barbase, idx, h0mask, exch, lane, u0, m0,
                                             xn, ys, h0buf, Wih0, Whh0, bih0, bhh0);
  } else {
    int rank = idx - 16;   // role-local; rank&7 == idx&7 so fallback unchanged
    int u0 = (rank * 2 + sub) * 16;
    if (wr == 0)
      wave_run<1, 16, H_, 0, 0, true, FAST>(barbase, rank, h0mask, exch, lane, u0, m0,
                                            xn, ys, h0buf, Wih1, Whh1, bih1, bhh1);
    else
      wave_run<1, 0, H_, 16, 0, false, FAST>(barbase, rank, h0mask, exch, lane, u0, m0,
                                             xn, ys, h0buf, Wih1, Whh1, bih1, bhh1);
  }
}

__launch_bounds__(256, 1)
__global__ void rnn_kernel(const unsigned short* __restrict__ xn,
                           unsigned short* __restrict__ ys,
                           unsigned short* __restrict__ h0buf,
                           unsigned* __restrict__ bar,
                           unsigned* __restrict__ xcdtab,
                           unsigned h0mask, int allowfast,
                           const float* __restrict__ Wih0, const float* __restrict__ Whh0,
                           const float* __restrict__ bih0, const float* __restrict__ bhh0,
                           const float* __restrict__ Wih1, const float* __restrict__ Whh1,
                           const float* __restrict__ bih1, const float* __restrict__ bhh1) {
  __shared__ float exch[2][3][64][4];
  __shared__ unsigned s_x[256];

  // ---- prologue: XCD roster (one-time, agent scope, model-correct fences) ----
  int xcd;
  asm volatile("s_getreg_b32 %0, hwreg(HW_REG_XCC_ID)" : "=s"(xcd));
  xcd &= 7;
  bool sawall = true;
  if (threadIdx.x == 0) {
    __hip_atomic_store(&xcdtab[blockIdx.x], (unsigned)xcd, __ATOMIC_RELAXED,
                       __HIP_MEMORY_SCOPE_AGENT);
    __threadfence();   // release: roster entry at coherence point before arrival
    __hip_atomic_fetch_add(&xcdtab[256], 1u, __ATOMIC_RELAXED,
                           __HIP_MEMORY_SCOPE_AGENT);
    unsigned got, spins = 0;
    do {
      __builtin_amdgcn_s_sleep(8);
      got = __hip_atomic_load(&xcdtab[256], __ATOMIC_RELAXED,
                              __HIP_MEMORY_SCOPE_AGENT);
      if (++spins > (1u << 16)) break;   // distress valve
    } while (got < 256u);
    sawall = (got >= 256u);
    __threadfence();   // acquire: subsequent roster reads see all entries
    s_x[0] = sawall ? 1u : 0u;
  }
  __syncthreads();
  sawall = (s_x[0] != 0u);
  __syncthreads();
  s_x[threadIdx.x] = __hip_atomic_load(&xcdtab[threadIdx.x], __ATOMIC_RELAXED,
                                       __HIP_MEMORY_SCOPE_AGENT);
  __syncthreads();
  if (threadIdx.x == 0) {
    int cnt[8] = {0, 0, 0, 0, 0, 0, 0, 0};
    int rank = 0;
    for (int j = 0; j < 256; ++j) {
      unsigned x = s_x[j] & 7u;
      cnt[x]++;
      if (j < (int)blockIdx.x && x == (unsigned)xcd) rank++;
    }
    bool ok = sawall;
#pragma unroll
    for (int k = 0; k < 8; ++k) ok = ok && (cnt[k] == 32);
    s_x[0] = ok ? 1u : 0u;
    s_x[1] = (unsigned)rank;
  }
  __syncthreads();
  const bool fastp = (s_x[0] != 0u) && (allowfast != 0);
  const int ridx = (int)s_x[1];

  const int wave = threadIdx.x >> 6;
  const int lane = threadIdx.x & 63;

  if (fastp) {
    const int grp = xcd;                 // group = physical XCD
    run_roles<true>(grp, ridx, wave, lane, h0mask, exch, bar + grp * (64 * 32),
                    xn, ys, h0buf, Wih0, Whh0, bih0, bhh0,
                    Wih1, Whh1, bih1, bhh1);
  } else {
    const int grp = (int)(blockIdx.x & 7);
    const int idx = (int)(blockIdx.x >> 3);
    run_roles<false>(grp, idx, wave, lane, h0mask, exch, bar + grp * (64 * 32),
                     xn, ys, h0buf, Wih0, Whh0, bih0, bhh0,
                     Wih1, Whh1, bih1, bhh1);
  }
}

// ---------------------------------------------------------------------------
// Output projection (65536 x 80, K=512) + inverse RevIN, MFMA.
// grid = 512 m-chunks * 5 n-tiles = 2560 blocks x 64 threads (1 wave).
// ---------------------------------------------------------------------------
__global__ void out_kernel(const unsigned short* __restrict__ ys,
                           const float* __restrict__ Wout, const float* __restrict__ bout,
                           const float* __restrict__ w_o, const float* __restrict__ b_o,
                           const float* __restrict__ w_c, const float* __restrict__ b_c,
                           const float* __restrict__ stats,
                           float* __restrict__ dout) {
  int lane = threadIdx.x;
  int quad = lane >> 4, l16 = lane & 15;
  int nb = blockIdx.x % 5, mc = blockIdx.x / 5;
  int ch = nb * 16 + l16;

  bf16x8 BW[16];
#pragma unroll
  for (int c = 0; c < 16; ++c)
    BW[c] = cvt_frag(Wout + (size_t)ch * 512 + 32 * c + quad * 8);
  float bo = bout[ch];
  float rb, rw; const float* mm; const float* ss; int cs, cidx;
  if (ch < 16) { rb = b_o[ch]; rw = w_o[ch]; mm = stats + ST_OM; ss = stats + ST_OSD; cs = 16; cidx = ch; }
  else         { rb = b_c[ch - 16]; rw = w_c[ch - 16]; mm = stats + ST_CM; ss = stats + ST_CSD; cs = 64; cidx = ch - 16; }

  for (int i = 0; i < 8; ++i) {
    int mt = mc * 8 + i;
    const unsigned short* A = ys + (size_t)(mt * 16 + l16) * 512;
    f32x4 acc = {0.f, 0.f, 0.f, 0.f};
#pragma unroll
    for (int c = 0; c < 16; ++c)
      acc = mfma16(load_bf8(A + 32 * c + quad * 8), BW[c], acc);
#pragma unroll
    for (int r = 0; r < 4; ++r) {
      int rr = mt * 16 + quad * 4 + r;
      int t = rr >> 7;
      int b = rr & 127;
      float m = mm[b * cs + cidx], sd = ss[b * cs + cidx];
      float v = (acc[r] + bo - rb) / rw * (sd + EPSR) + m;
      size_t off = (ch < 16)
          ? ((size_t)b * 8192 + (size_t)t * 16 + ch)
          : ((size_t)1048576 + (size_t)b * 32768 + (size_t)t * 64 + (ch - 16));
      dout[off] = v;
    }
  }
}

// ---------------------------------------------------------------------------
extern "C" void kernel_launch(void* const* d_in, const int* in_sizes, int n_in,
                              void* d_out, int out_size, void* d_ws, size_t ws_size,
                              hipStream_t stream) {
  const float* cov  = (const float*)d_in[0];
  const float* trt  = (const float*)d_in[1];
  const float* outh = (const float*)d_in[2];
  const float* Wih0 = (const float*)d_in[3];
  const float* Whh0 = (const float*)d_in[4];
  const float* bih0 = (const float*)d_in[5];
  const float* bhh0 = (const float*)d_in[6];
  const float* Wih1 = (const float*)d_in[7];
  const float* Whh1 = (const float*)d_in[8];
  const float* bih1 = (const float*)d_in[9];
  const float* bhh1 = (const float*)d_in[10];
  const float* Wout = (const float*)d_in[11];
  const float* bout = (const float*)d_in[12];
  const float* w_t  = (const float*)d_in[13];
  const float* b_t  = (const float*)d_in[14];
  const float* w_o  = (const float*)d_in[15];
  const float* b_o  = (const float*)d_in[16];
  const float* w_c  = (const float*)d_in[17];
  const float* b_c  = (const float*)d_in[18];

  char* ws = (char*)d_ws;
  unsigned short* xn = (unsigned short*)(ws + XN_OFF);
  unsigned short* ys = (unsigned short*)(ws + YS_OFF);

  // Unique-h0 layout if workspace allows; else compact (R5) layout.
  const size_t u_h0   = YS_OFF + YS_BYTES;
  const size_t u_bar  = u_h0 + H0U_BYTES;
  const size_t u_xcdt = u_bar + BAR_BYTES;
  const size_t u_st   = u_xcdt + XCDT_BYTES;
  const size_t u_need = u_st + STATS_BYTES;
  const bool uniq = (ws_size >= u_need);

  unsigned short* h0;
  unsigned *bar, *xcdt;
  float* stats;
  unsigned h0mask;
  int allowfast;
  if (uniq) {
    h0    = (unsigned short*)(ws + u_h0);
    bar   = (unsigned*)(ws + u_bar);
    xcdt  = (unsigned*)(ws + u_xcdt);
    stats = (float*)(ws + u_st);
    h0mask = 1023u;        // slot = t (t <= 513)
    allowfast = 1;
    // ws re-poisoned to 0xAA before every launch: zero h0 slot 0 + barriers
    // + roster. (Slots 1..512 are written before read.)
    (void)hipMemsetAsync((void*)(ws + u_h0), 0, H0SLOT_BYTES, stream);
    (void)hipMemsetAsync((void*)(ws + u_bar), 0, BAR_BYTES + XCDT_BYTES, stream);
  } else {
    h0    = (unsigned short*)(ws + H0_OFF);
    bar   = (unsigned*)(ws + H0_OFF + H0_BYTES);
    xcdt  = (unsigned*)(ws + H0_OFF + H0_BYTES + BAR_BYTES);
    stats = (float*)(ws + H0_OFF + H0_BYTES + BAR_BYTES + XCDT_BYTES);
    h0mask = 1u;           // ping-pong (agent-scope fallback only)
    allowfast = 0;
    (void)hipMemsetAsync((void*)(ws + H0_OFF), 0,
                         H0_BYTES + BAR_BYTES + XCDT_BYTES, stream);
  }

  stats_kernel<<<128, 128, 0, stream>>>(trt, outh, cov, stats);
  norm_kernel<<<(L_ * B_ * CI_) / 256, 256, 0, stream>>>(
      trt, outh, cov, stats, w_t, b_t, w_o, b_o, w_c, b_c, xn);

  rnn_kernel<<<256, 256, 0, stream>>>(xn, ys, h0, bar, xcdt, h0mask, allowfast,
                                      Wih0, Whh0, bih0, bhh0,
                                      Wih1, Whh1, bih1, bhh1);

  out_kernel<<<2560, 64, 0, stream>>>(ys, Wout, bout, w_o, b_o, w_c, b_c,
                                      stats, (float*)d_out);
}